// Round 7
// baseline (150.328 us; speedup 1.0000x reference)
//
#include <hip/hip_runtime.h>

// Inverse Haar wavelet 2D (fp32):
//   x:       [B=16, 4C=256, H=128, W=128]
//   filters: [4C,1,2,2] viewed as [C,4,2,2]
//   out:     [B, C=64, 256, 256]
// out[b][c][2h+p][2w+q] = sum_k x[b][4c+k][h][w] * f[c][k][p][q]
//
// v4: R4's winning wide-grid structure + deeper per-thread MLP.
// Each thread processes 4 consecutive h rows (fully unrolled -> 16
// independent float4 loads in flight), 4096 blocks keep the device
// oversubscribed. Streams advance sequentially 512B/iter per plane.

typedef float f32x4 __attribute__((ext_vector_type(4)));

#define BB 16
#define CC 64
#define HH 128
#define WW 128
#define W4 (WW / 4)            // 32 column-quads per row
#define HITER 4                // rows per thread
#define HQ (HH / HITER)        // 32 h-groups
#define NTHREADS (BB * CC * HQ * W4)   // 1,048,576 -> 4096 blocks

__global__ __launch_bounds__(256) void ihaar2d_kernel(
    const float* __restrict__ x,
    const float* __restrict__ filt,
    float* __restrict__ out)
{
    const int t  = blockIdx.x * 256 + threadIdx.x;
    const int w4 = t & (W4 - 1);           // 5 bits
    const int hq = (t >> 5) & (HQ - 1);    // 5 bits
    const int c  = (t >> 10) & (CC - 1);   // 6 bits
    const int b  = t >> 16;

    // Per-channel Haar taps: f[k] = {p0q0, p0q1, p1q0, p1q1}
    const f32x4* ff = (const f32x4*)(filt + c * 16);
    const f32x4 f0 = ff[0], f1 = ff[1], f2 = ff[2], f3 = ff[3];

    const int plane = HH * WW;             // 16384 floats (64KB)
    const int h0    = hq * HITER;
    const float* xr = x + ((b * (4 * CC) + c * 4) * HH + h0) * WW + w4 * 4;
    float*       oq = out + ((b * CC + c) * (2 * HH) + 2 * h0) * (2 * WW) + w4 * 8;

#pragma unroll
    for (int i = 0; i < HITER; ++i) {
        const float* xi = xr + i * WW;
        const f32x4 a0 = __builtin_nontemporal_load((const f32x4*)(xi + 0 * plane));
        const f32x4 a1 = __builtin_nontemporal_load((const f32x4*)(xi + 1 * plane));
        const f32x4 a2 = __builtin_nontemporal_load((const f32x4*)(xi + 2 * plane));
        const f32x4 a3 = __builtin_nontemporal_load((const f32x4*)(xi + 3 * plane));

        f32x4 r0a, r0b, r1a, r1b;  // rows 2h (8 floats) and 2h+1 (8 floats)
        r0a.x = a0.x * f0.x + a1.x * f1.x + a2.x * f2.x + a3.x * f3.x;
        r0a.y = a0.x * f0.y + a1.x * f1.y + a2.x * f2.y + a3.x * f3.y;
        r0a.z = a0.y * f0.x + a1.y * f1.x + a2.y * f2.x + a3.y * f3.x;
        r0a.w = a0.y * f0.y + a1.y * f1.y + a2.y * f2.y + a3.y * f3.y;
        r0b.x = a0.z * f0.x + a1.z * f1.x + a2.z * f2.x + a3.z * f3.x;
        r0b.y = a0.z * f0.y + a1.z * f1.y + a2.z * f2.y + a3.z * f3.y;
        r0b.z = a0.w * f0.x + a1.w * f1.x + a2.w * f2.x + a3.w * f3.x;
        r0b.w = a0.w * f0.y + a1.w * f1.y + a2.w * f2.y + a3.w * f3.y;

        r1a.x = a0.x * f0.z + a1.x * f1.z + a2.x * f2.z + a3.x * f3.z;
        r1a.y = a0.x * f0.w + a1.x * f1.w + a2.x * f2.w + a3.x * f3.w;
        r1a.z = a0.y * f0.z + a1.y * f1.z + a2.y * f2.z + a3.y * f3.z;
        r1a.w = a0.y * f0.w + a1.y * f1.w + a2.y * f2.w + a3.y * f3.w;
        r1b.x = a0.z * f0.z + a1.z * f1.z + a2.z * f2.z + a3.z * f3.z;
        r1b.y = a0.z * f0.w + a1.z * f1.w + a2.z * f2.w + a3.z * f3.w;
        r1b.z = a0.w * f0.z + a1.w * f1.z + a2.w * f2.z + a3.w * f3.z;
        r1b.w = a0.w * f0.w + a1.w * f1.w + a2.w * f2.w + a3.w * f3.w;

        float* o0 = oq + i * 2 * (2 * WW);
        float* o1 = o0 + 2 * WW;
        __builtin_nontemporal_store(r0a, (f32x4*)o0);
        __builtin_nontemporal_store(r0b, (f32x4*)(o0 + 4));
        __builtin_nontemporal_store(r1a, (f32x4*)o1);
        __builtin_nontemporal_store(r1b, (f32x4*)(o1 + 4));
    }
}

extern "C" void kernel_launch(void* const* d_in, const int* in_sizes, int n_in,
                              void* d_out, int out_size, void* d_ws, size_t ws_size,
                              hipStream_t stream) {
    const float* x    = (const float*)d_in[0];
    const float* filt = (const float*)d_in[1];
    float* out        = (float*)d_out;

    const int threads = 256;
    const int blocks  = NTHREADS / threads;   // 4096 blocks = 16 per CU
    ihaar2d_kernel<<<blocks, threads, 0, stream>>>(x, filt, out);
}

// Round 8
// 81.952 us; speedup vs baseline: 1.8343x; 1.8343x over previous
//
#include <hip/hip_runtime.h>

// Inverse Haar wavelet 2D (fp32):
//   x:       [B=16, 4C=256, H=128, W=128]
//   filters: [4C,1,2,2] viewed as [C,4,2,2]
//   out:     [B, C=64, 256, 256]
// out[b][c][2h+p][2w+q] = sum_k x[b][4c+k][h][w] * f[c][k][p][q]
//
// v5: max concurrency (8.4M one-shot threads, 32768 blocks) + fully-dense
// PLAIN stores (one float4/lane, contiguous across the wave -> every 64B
// line filled by a single instruction, L2 combines freely) + NT loads only
// (read-once data bypasses L2, leaving L2 capacity for the write path).
// R7 post-mortem: NT + half-dense stores caused 1.42x write amplification.

typedef float f32x2 __attribute__((ext_vector_type(2)));
typedef float f32x4 __attribute__((ext_vector_type(4)));

#define BB 16
#define CC 64
#define HH 128
#define WW 128
#define W2 (WW / 2)                       // 64 column-pairs: one wave = one row
#define NTHREADS (BB * CC * HH * W2)      // 8,388,608 -> 32768 blocks

__global__ __launch_bounds__(256) void ihaar2d_kernel(
    const float* __restrict__ x,
    const float* __restrict__ filt,
    float* __restrict__ out)
{
    const int t  = blockIdx.x * 256 + threadIdx.x;
    const int w2 = t & (W2 - 1);           // 6 bits -> wave spans a full row
    const int h  = (t >> 6) & (HH - 1);    // 7 bits
    const int c  = (t >> 13) & (CC - 1);   // 6 bits
    const int b  = t >> 19;

    // Per-channel Haar taps: f[k] = {p0q0, p0q1, p1q0, p1q1}
    const f32x4* ff = (const f32x4*)(filt + c * 16);
    const f32x4 f0 = ff[0], f1 = ff[1], f2 = ff[2], f3 = ff[3];

    const int plane = HH * WW;             // 16384 floats
    const float* xb = x + ((b * (4 * CC) + c * 4) * HH + h) * WW + w2 * 2;

    // NT loads: read-once, keep out of L2
    const f32x2 a0 = __builtin_nontemporal_load((const f32x2*)(xb + 0 * plane));
    const f32x2 a1 = __builtin_nontemporal_load((const f32x2*)(xb + 1 * plane));
    const f32x2 a2 = __builtin_nontemporal_load((const f32x2*)(xb + 2 * plane));
    const f32x2 a3 = __builtin_nontemporal_load((const f32x2*)(xb + 3 * plane));

    f32x4 r0, r1;   // output rows 2h and 2h+1, cols [4*w2, 4*w2+4)
    r0.x = a0.x * f0.x + a1.x * f1.x + a2.x * f2.x + a3.x * f3.x;
    r0.y = a0.x * f0.y + a1.x * f1.y + a2.x * f2.y + a3.x * f3.y;
    r0.z = a0.y * f0.x + a1.y * f1.x + a2.y * f2.x + a3.y * f3.x;
    r0.w = a0.y * f0.y + a1.y * f1.y + a2.y * f2.y + a3.y * f3.y;
    r1.x = a0.x * f0.z + a1.x * f1.z + a2.x * f2.z + a3.x * f3.z;
    r1.y = a0.x * f0.w + a1.x * f1.w + a2.x * f2.w + a3.x * f3.w;
    r1.z = a0.y * f0.z + a1.y * f1.z + a2.y * f2.z + a3.y * f3.z;
    r1.w = a0.y * f0.w + a1.y * f1.w + a2.y * f2.w + a3.y * f3.w;

    // Plain (cached) stores: dense across the wave, L2 write path untouched
    float* o = out + ((b * CC + c) * (2 * HH) + 2 * h) * (2 * WW) + w2 * 4;
    *(f32x4*)o            = r0;
    *(f32x4*)(o + 2 * WW) = r1;
}

extern "C" void kernel_launch(void* const* d_in, const int* in_sizes, int n_in,
                              void* d_out, int out_size, void* d_ws, size_t ws_size,
                              hipStream_t stream) {
    const float* x    = (const float*)d_in[0];
    const float* filt = (const float*)d_in[1];
    float* out        = (float*)d_out;

    const int threads = 256;
    const int blocks  = NTHREADS / threads;   // 32768 blocks
    ihaar2d_kernel<<<blocks, threads, 0, stream>>>(x, filt, out);
}